// Round 9
// baseline (634.729 us; speedup 1.0000x reference)
//
#include <hip/hip_runtime.h>

// CTRNN forward, B=256 T=2048 D=32 H=64. ALL tensors fp32.
// r12: single-kernel block-level fusion. r8 post-mortem: R/Q sweep is
// codegen lottery (R=16 regressed despite lower modeled stall); best proven
// recur step = r7 (R=8/Q=14, 333us), best xproj = r6 LDS-staged (~170us).
// The remaining structural waste: the two kernels serialize GLOBALLY —
// every batch's recurrence waits for all batches' xproj, and xp does a
// 256MB HBM round-trip. Fix: one wave per batch, per-128-step tiles:
//   phase1: stage 128 x rows (16KB) into LDS coalesced (r6 pattern, NOT
//           r3's wave-uniform loads), compute xp rows -> 32KB LDS buffer.
//   phase2: 128 steps of the r7-EXACT step, xp read from LDS (b32, 2-way
//           bank alias = free), no global xp load, h stores unchanged.
// xp math and recur math are verbatim copies -> bit-identical, absmax
// must stay 0.0078125. No barriers anywhere (single wave; LDS in-order).

#define Bb 256
#define Tt 2048
#define Dd 32
#define Hh 64
#define TILE 128
#define NT (Tt / TILE)

typedef float v2f __attribute__((ext_vector_type(2)));
typedef float v4f __attribute__((ext_vector_type(4)));

static constexpr float ALPHA = (float)(16.67 / 40.0);
static constexpr float OMA   = 1.0f - ALPHA;

static __device__ inline v2f vfma2(v2f a, v2f b, v2f c) {
#if __has_builtin(__builtin_elementwise_fma)
    return __builtin_elementwise_fma(a, b, c);
#else
    v2f r; r.x = fmaf(a.x, b.x, c.x); r.y = fmaf(a.y, b.y, c.y); return r;
#endif
}

__global__ __launch_bounds__(64, 1) void ctrnn_fused(
    const float* __restrict__ x,
    const float* __restrict__ W_in,
    const float* __restrict__ b_in,
    const float* __restrict__ W_hh,
    const float* __restrict__ b_hh,
    float* __restrict__ out)
{
    const int b    = blockIdx.x;
    const int lane = threadIdx.x;

    __shared__ alignas(16) float xstage[TILE * Dd];   // 16 KB: x rows
    __shared__ alignas(16) float xpb[TILE * Hh];      // 32 KB: xp rows
    __shared__ alignas(16) float hs[Hh];              // 256 B: h broadcast

    // W_in row of this lane as v2f pairs (xproj pairing, verbatim)
    v2f w[16];
    const v2f* wir = reinterpret_cast<const v2f*>(W_in + lane * Dd);
#pragma unroll
    for (int j = 0; j < 16; ++j) w[j] = wir[j];

    // W_hh row of this lane as v4f: w4[k] = W_hh[lane][4k..4k+3]
    v4f w4[16];
    const v4f* wr = reinterpret_cast<const v4f*>(W_hh + lane * Hh);
#pragma unroll
    for (int j = 0; j < 16; ++j) w4[j] = wr[j];

    const float cb = ALPHA * (b_in[lane] + b_hh[lane]);

    const float4* xsrc_base = reinterpret_cast<const float4*>(
        x + (size_t)b * Tt * Dd);                     // 8 float4 per row
    float* op = out + (size_t)b * Tt * Hh + lane;

    const v4f*  h4    = reinterpret_cast<const v4f*>(hs);
    float4*     xdst4 = reinterpret_cast<float4*>(xstage);

    // h prologue: h_0 = 0; q0..q13 hold h[8..63] of the upcoming step
    hs[lane] = 0.0f;   // single wave: in-order LDS pipe orders later reads
    v4f q0  = h4[2],  q1  = h4[3],  q2  = h4[4],  q3  = h4[5];
    v4f q4  = h4[6],  q5  = h4[7],  q6  = h4[8],  q7  = h4[9];
    v4f q8  = h4[10], q9  = h4[11], q10 = h4[12], q11 = h4[13];
    v4f q12 = h4[14], q13 = h4[15];

    float hold = 0.0f;
    float pre  = cb;              // fmaf(OMA, 0, cb) == cb exactly

    for (int n = 0; n < NT; ++n) {
        // ---------------- phase 1: stage x tile, compute xp tile ----------
        // coalesced stage: 128 rows x 32 f = 1024 float4; lane-strided.
        const float4* xsrc = xsrc_base + (size_t)n * TILE * (Dd / 4);
#pragma unroll
        for (int i = 0; i < 16; ++i)
            xdst4[i * 64 + lane] = xsrc[i * 64 + lane];

        // xp rows: broadcast-read x row from LDS, per-lane W_in dot.
        // Math verbatim from the passing xproj kernel -> bit-identical.
#pragma unroll 2
        for (int i = 0; i < TILE; ++i) {
            const float4* xr = reinterpret_cast<const float4*>(xstage + i * Dd);
            v2f a01 = {0.f, 0.f}, a23 = {0.f, 0.f};
#pragma unroll
            for (int j = 0; j < 8; ++j) {
                const float4 xv = xr[j];
                const v2f x01 = {xv.x, xv.y};
                const v2f x23 = {xv.z, xv.w};
                a01 = vfma2(w[2 * j + 0], x01, a01);
                a23 = vfma2(w[2 * j + 1], x23, a23);
            }
            xpb[i * Hh + lane] = (a01.x + a01.y) + (a23.x + a23.y);
        }

        // ---------------- phase 2: 128 recurrence steps (r7-exact) --------
        for (int tb = 0; tb < TILE; tb += 8) {
            float xp[8];
#pragma unroll
            for (int j = 0; j < 8; ++j) xp[j] = xpb[(tb + j) * Hh + lane];

#pragma unroll
            for (int j = 0; j < 8; ++j) {
                const int hb = __float_as_int(hold);
                float s0 = 0.f, s1 = 0.f, s2 = 0.f, s3 = 0.f;
                // cols 0..7 via readlane (ascending; fills LDS latency window)
#pragma unroll
                for (int k = 0; k < 2; ++k) {
                    const float h0 = __int_as_float(__builtin_amdgcn_readlane(hb, 4 * k + 0));
                    const float h1 = __int_as_float(__builtin_amdgcn_readlane(hb, 4 * k + 1));
                    const float h2 = __int_as_float(__builtin_amdgcn_readlane(hb, 4 * k + 2));
                    const float h3 = __int_as_float(__builtin_amdgcn_readlane(hb, 4 * k + 3));
                    s0 = fmaf(w4[k][0], h0, s0);   // col 4k
                    s1 = fmaf(w4[k][1], h1, s1);   // col 4k+1
                    s2 = fmaf(w4[k][2], h2, s2);   // col 4k+2
                    s3 = fmaf(w4[k][3], h3, s3);   // col 4k+3
                }
                // cols 8..63 from q via pk_fma; per-accumulator order
                // identical (s0: 8,12..60 asc; s1: 9..61; ...)
                v2f acc01 = {s0, s1}, acc23 = {s2, s3};
#define QPK(K, Q)                                                              \
                acc01 = vfma2(__builtin_shufflevector(w4[K], w4[K], 0, 1),     \
                              __builtin_shufflevector((Q), (Q), 0, 1), acc01); \
                acc23 = vfma2(__builtin_shufflevector(w4[K], w4[K], 2, 3),     \
                              __builtin_shufflevector((Q), (Q), 2, 3), acc23);
                QPK( 2, q0)  QPK( 3, q1)  QPK( 4, q2)  QPK( 5, q3)
                QPK( 6, q4)  QPK( 7, q5)  QPK( 8, q6)  QPK( 9, q7)
                QPK(10, q8)  QPK(11, q9)  QPK(12, q10) QPK(13, q11)
                QPK(14, q12) QPK(15, q13)
#undef QPK
                const v2f tt     = acc01 + acc23;           // {s0+s2, s1+s3}
                const float sum  = (tt.x + tt.y) + xp[j];
                const float hnew = fmaxf(fmaf(ALPHA, sum, pre), 0.0f);

                // publish h_t[8..63] for next iter, then immediately issue
                // the broadcast reads; latency hides under the next readlane
                // block + tail. sched_barrier pins the issue point.
                hs[lane] = hnew;
                q0  = h4[2];  q1  = h4[3];  q2  = h4[4];  q3  = h4[5];
                q4  = h4[6];  q5  = h4[7];  q6  = h4[8];  q7  = h4[9];
                q8  = h4[10]; q9  = h4[11]; q10 = h4[12]; q11 = h4[13];
                q12 = h4[14]; q13 = h4[15];
                __builtin_amdgcn_sched_barrier(0);

                *op = hnew;                    // h store (coalesced 256B)
                op += Hh;
                hold = hnew;
                pre  = fmaf(OMA, hnew, cb);    // next step's pre, in shadow
            }
        }
    }
    // h_last
    out[(size_t)Bb * Tt * Hh + (size_t)b * Hh + lane] = hold;
}

extern "C" void kernel_launch(void* const* d_in, const int* in_sizes, int n_in,
                              void* d_out, int out_size, void* d_ws, size_t ws_size,
                              hipStream_t stream) {
    const float* x    = (const float*)d_in[0];
    // d_in[1] = seq_lengths (int32): forward value is mask-independent.
    const float* W_in = (const float*)d_in[2];
    const float* b_in = (const float*)d_in[3];
    const float* W_hh = (const float*)d_in[4];
    const float* b_hh = (const float*)d_in[5];
    float* out = (float*)d_out;

    ctrnn_fused<<<dim3(Bb), dim3(64), 0, stream>>>(x, W_in, b_in, W_hh, b_hh, out);
}